// Round 1
// baseline (335.261 us; speedup 1.0000x reference)
//
#include <hip/hip_runtime.h>

// Topo_Attention: out[b,c,t] = softmax_c( sum_l w[l]*tanh(sum_m v[l,m]*h_c[b,t,m]) )
// B=32, T=4096, M=256, L=128.  Strategy: bf16 MFMA GEMM (memory-bound, ~43us floor).

typedef unsigned short u16;
typedef unsigned int   u32;
typedef __bf16 bf16x8 __attribute__((ext_vector_type(8)));
typedef float  f32x4  __attribute__((ext_vector_type(4)));

union ABFrag { bf16x8 v; u16 u[8]; uint4 q4; };

__device__ __forceinline__ u16 f2bf(float f) {
  // round-to-nearest-even fp32 -> bf16 (inputs are finite randn; no NaN path needed)
  u32 u = __float_as_uint(f);
  u += 0x7fffu + ((u >> 16) & 1u);
  return (u16)(u >> 16);
}

__device__ __forceinline__ float fast_tanh(float x) {
  // tanh(x) = 1 - 2/(e^{2x}+1);  e^{2x} = 2^{x*2.885390082}
  float t = __builtin_amdgcn_exp2f(2.885390082f * x);
  return 1.0f - 2.0f * __builtin_amdgcn_rcpf(t + 1.0f);
}

#define NWG   512     // 2 workgroups per CU (LDS = 64KB each)
#define ITERS 4       // 2048 total WG-iters of 64 rows

__global__ __launch_bounds__(256, 2) void topo_attn_kernel(
    const float* __restrict__ h1, const float* __restrict__ h2,
    const float* __restrict__ w,  const float* __restrict__ vfp,
    float* __restrict__ out) {
  // V in bf16, rotate-swizzled: element (l,m) at l*256 + ((m/8 + l)%32)*8 + m%8.
  // Makes the per-(lt,ks) ds_read_b128 conflict-free with zero padding (64KB exact).
  __shared__ __align__(16) u16 vlds[128 * 256];

  const int tid = threadIdx.x;

  { // one-time: convert V fp32 -> bf16 into LDS (V is L2/L3-hot across WGs)
    const float4* src = (const float4*)vfp;
    #pragma unroll
    for (int k = 0; k < 16; ++k) {
      int gi = k * 256 + tid;          // 8-element group index, 0..4095
      float4 f0 = src[gi * 2];
      float4 f1 = src[gi * 2 + 1];
      ABFrag t;
      t.u[0] = f2bf(f0.x); t.u[1] = f2bf(f0.y); t.u[2] = f2bf(f0.z); t.u[3] = f2bf(f0.w);
      t.u[4] = f2bf(f1.x); t.u[5] = f2bf(f1.y); t.u[6] = f2bf(f1.z); t.u[7] = f2bf(f1.w);
      int e0 = gi << 3;
      int l  = e0 >> 8;                // 0..127
      int g  = (e0 & 255) >> 3;        // 0..31
      *(uint4*)&vlds[(l << 8) + (((g + l) & 31) << 3)] = t.q4;
    }
  }
  __syncthreads();

  const int lane = tid & 63;
  const int wave = tid >> 6;
  const int l15  = lane & 15;          // MFMA: A-row / B-col / D-col lane index
  const int q    = lane >> 4;          // quad: A/B k = q*8+j ; D row = q*4+reg

  float wreg[8];
  #pragma unroll
  for (int lt = 0; lt < 8; ++lt) wreg[lt] = w[lt * 16 + l15];

  for (int it = 0; it < ITERS; ++it) {
    const int wgIter = blockIdx.x + it * NWG;          // 0..2047
    const int n0 = (wgIter * 4 + wave) << 4;           // 16 rows per wave
    const float4* p1 = (const float4*)(h1 + (size_t)(n0 + l15) * 256) + q * 2;
    const float4* p2 = (const float4*)(h2 + (size_t)(n0 + l15) * 256) + q * 2;

    f32x4 acc0[8], acc1[8];
    #pragma unroll
    for (int lt = 0; lt < 8; ++lt) {
      acc0[lt] = (f32x4){0.f, 0.f, 0.f, 0.f};
      acc1[lt] = (f32x4){0.f, 0.f, 0.f, 0.f};
    }

    #pragma unroll
    for (int ks = 0; ks < 8; ++ks) {
      // A-frags: lane holds rows n0+l15, k = 32*ks + q*8 + j  (32B contiguous)
      float4 ra = p1[8 * ks], rb = p1[8 * ks + 1];
      float4 rc = p2[8 * ks], rd = p2[8 * ks + 1];
      ABFrag a1, a2;
      a1.u[0] = f2bf(ra.x); a1.u[1] = f2bf(ra.y); a1.u[2] = f2bf(ra.z); a1.u[3] = f2bf(ra.w);
      a1.u[4] = f2bf(rb.x); a1.u[5] = f2bf(rb.y); a1.u[6] = f2bf(rb.z); a1.u[7] = f2bf(rb.w);
      a2.u[0] = f2bf(rc.x); a2.u[1] = f2bf(rc.y); a2.u[2] = f2bf(rc.z); a2.u[3] = f2bf(rc.w);
      a2.u[4] = f2bf(rd.x); a2.u[5] = f2bf(rd.y); a2.u[6] = f2bf(rd.z); a2.u[7] = f2bf(rd.w);
      #pragma unroll
      for (int lt = 0; lt < 8; ++lt) {
        const int l = (lt << 4) + l15;
        bf16x8 bf = *(const bf16x8*)&vlds[(l << 8) + (((4 * ks + q + l) & 31) << 3)];
        acc0[lt] = __builtin_amdgcn_mfma_f32_16x16x32_bf16(a1.v, bf, acc0[lt], 0, 0, 0);
        acc1[lt] = __builtin_amdgcn_mfma_f32_16x16x32_bf16(a2.v, bf, acc1[lt], 0, 0, 0);
      }
    }

    // Epilogue: scores = sum_l w[l]*tanh(temp[l]); D layout: col L = 16*lt+l15, row = q*4+r
    float s0p[4] = {0.f, 0.f, 0.f, 0.f};
    float s1p[4] = {0.f, 0.f, 0.f, 0.f};
    #pragma unroll
    for (int lt = 0; lt < 8; ++lt) {
      #pragma unroll
      for (int r = 0; r < 4; ++r) {
        s0p[r] += wreg[lt] * fast_tanh(acc0[lt][r]);
        s1p[r] += wreg[lt] * fast_tanh(acc1[lt][r]);
      }
    }
    // reduce over the 16 L-lanes (xor within 16-lane group)
    #pragma unroll
    for (int r = 0; r < 4; ++r) {
      #pragma unroll
      for (int off = 1; off < 16; off <<= 1) {
        s0p[r] += __shfl_xor(s0p[r], off);
        s1p[r] += __shfl_xor(s1p[r], off);
      }
    }
    if (l15 < 4) {
      float s0 = (l15 == 0) ? s0p[0] : (l15 == 1) ? s0p[1] : (l15 == 2) ? s0p[2] : s0p[3];
      float s1 = (l15 == 0) ? s1p[0] : (l15 == 1) ? s1p[1] : (l15 == 2) ? s1p[2] : s1p[3];
      int n = n0 + q * 4 + l15;
      int b = n >> 12, t = n & 4095;
      // softmax over 2: a0 = sigmoid(s0-s1)
      float e  = __builtin_amdgcn_exp2f(-1.442695041f * (s0 - s1));
      float a0 = __builtin_amdgcn_rcpf(1.0f + e);
      out[b * 8192 + t]        = a0;
      out[b * 8192 + 4096 + t] = 1.0f - a0;
    }
  }
}

extern "C" void kernel_launch(void* const* d_in, const int* in_sizes, int n_in,
                              void* d_out, int out_size, void* d_ws, size_t ws_size,
                              hipStream_t stream) {
  const float* h1 = (const float*)d_in[0];   // (32,4096,256) fp32
  const float* h2 = (const float*)d_in[1];   // (32,4096,256) fp32
  const float* w  = (const float*)d_in[2];   // (1,128) fp32
  const float* v  = (const float*)d_in[3];   // (128,256) fp32
  float* out = (float*)d_out;                // (32,2,4096) fp32

  topo_attn_kernel<<<NWG, 256, 0, stream>>>(h1, h2, w, v, out);
}

// Round 2
// 306.364 us; speedup vs baseline: 1.0943x; 1.0943x over previous
//
#include <hip/hip_runtime.h>

// Topo_Attention: out[b,c,t] = softmax_c( sum_l w[l]*tanh(sum_m v[l,m]*h_c[b,t,m]) )
// B=32, T=4096, M=256, L=128.  bf16 MFMA GEMM; memory-bound, HBM floor ~43us.
// R2: 512-thread WGs -> 16 waves/CU (4/SIMD) for latency hiding. Same numerics as R1.

typedef unsigned short u16;
typedef unsigned int   u32;
typedef __bf16 bf16x8 __attribute__((ext_vector_type(8)));
typedef float  f32x4  __attribute__((ext_vector_type(4)));

union ABFrag { bf16x8 v; u16 u[8]; uint4 q4; };

__device__ __forceinline__ u16 f2bf(float f) {
  // round-to-nearest-even fp32 -> bf16 (finite inputs; no NaN path)
  u32 u = __float_as_uint(f);
  u += 0x7fffu + ((u >> 16) & 1u);
  return (u16)(u >> 16);
}

__device__ __forceinline__ float fast_tanh(float x) {
  // tanh(x) = 1 - 2/(e^{2x}+1);  e^{2x} = 2^{x*2.885390082}
  float t = __builtin_amdgcn_exp2f(2.885390082f * x);
  return 1.0f - 2.0f * __builtin_amdgcn_rcpf(t + 1.0f);
}

#define NWG   512     // 2 workgroups per CU (LDS 64KB each, 128KB of 160KB used)
#define ITERS 2       // 512 WGs x 8 waves x 16 rows x 2 iters = 131072 rows

__global__ __launch_bounds__(512, 4) void topo_attn_kernel(
    const float* __restrict__ h1, const float* __restrict__ h2,
    const float* __restrict__ w,  const float* __restrict__ vfp,
    float* __restrict__ out) {
  // V in bf16, rotate-swizzled: element (l,m) at l*256 + ((m/8 + l)%32)*8 + m%8.
  // Conflict-light ds_read_b128 with zero padding (exactly 64KB -> 2 WGs/CU).
  __shared__ __align__(16) u16 vlds[128 * 256];

  const int tid = threadIdx.x;

  { // one-time: convert V fp32 -> bf16 into LDS (V stays L2-hot across WGs)
    const float4* src = (const float4*)vfp;
    #pragma unroll
    for (int k = 0; k < 8; ++k) {
      int gi = k * 512 + tid;          // 8-element group index, 0..4095
      float4 f0 = src[gi * 2];
      float4 f1 = src[gi * 2 + 1];
      ABFrag t;
      t.u[0] = f2bf(f0.x); t.u[1] = f2bf(f0.y); t.u[2] = f2bf(f0.z); t.u[3] = f2bf(f0.w);
      t.u[4] = f2bf(f1.x); t.u[5] = f2bf(f1.y); t.u[6] = f2bf(f1.z); t.u[7] = f2bf(f1.w);
      int e0 = gi << 3;
      int l  = e0 >> 8;                // 0..127
      int g  = (e0 & 255) >> 3;        // 0..31
      *(uint4*)&vlds[(l << 8) + (((g + l) & 31) << 3)] = t.q4;
    }
  }
  __syncthreads();

  const int lane = tid & 63;
  const int wave = tid >> 6;           // 0..7
  const int l15  = lane & 15;          // MFMA: A-row / B-col / D-col lane index
  const int q    = lane >> 4;          // quad: A/B k = q*8+j ; D row = q*4+reg

  float wreg[8];
  #pragma unroll
  for (int lt = 0; lt < 8; ++lt) wreg[lt] = w[lt * 16 + l15];

  #pragma unroll
  for (int it = 0; it < ITERS; ++it) {
    const int wgIter = blockIdx.x + it * NWG;          // 0..1023
    const int n0 = (wgIter * 8 + wave) << 4;           // 16 rows per wave
    const float4* p1 = (const float4*)(h1 + (size_t)(n0 + l15) * 256) + q * 2;
    const float4* p2 = (const float4*)(h2 + (size_t)(n0 + l15) * 256) + q * 2;

    f32x4 acc0[8], acc1[8];
    #pragma unroll
    for (int lt = 0; lt < 8; ++lt) {
      acc0[lt] = (f32x4){0.f, 0.f, 0.f, 0.f};
      acc1[lt] = (f32x4){0.f, 0.f, 0.f, 0.f};
    }

    #pragma unroll
    for (int ks = 0; ks < 8; ++ks) {
      // A-frags: lane holds row n0+l15, k = 32*ks + q*8 + j  (32B contiguous/lane;
      // the q-group x {ra,rb} covers a full 128B line per row)
      float4 ra = p1[8 * ks], rb = p1[8 * ks + 1];
      float4 rc = p2[8 * ks], rd = p2[8 * ks + 1];
      ABFrag a1, a2;
      a1.u[0] = f2bf(ra.x); a1.u[1] = f2bf(ra.y); a1.u[2] = f2bf(ra.z); a1.u[3] = f2bf(ra.w);
      a1.u[4] = f2bf(rb.x); a1.u[5] = f2bf(rb.y); a1.u[6] = f2bf(rb.z); a1.u[7] = f2bf(rb.w);
      a2.u[0] = f2bf(rc.x); a2.u[1] = f2bf(rc.y); a2.u[2] = f2bf(rc.z); a2.u[3] = f2bf(rc.w);
      a2.u[4] = f2bf(rd.x); a2.u[5] = f2bf(rd.y); a2.u[6] = f2bf(rd.z); a2.u[7] = f2bf(rd.w);
      #pragma unroll
      for (int lt = 0; lt < 8; ++lt) {
        const int l = (lt << 4) + l15;
        bf16x8 bf = *(const bf16x8*)&vlds[(l << 8) + (((4 * ks + q + l) & 31) << 3)];
        acc0[lt] = __builtin_amdgcn_mfma_f32_16x16x32_bf16(a1.v, bf, acc0[lt], 0, 0, 0);
        acc1[lt] = __builtin_amdgcn_mfma_f32_16x16x32_bf16(a2.v, bf, acc1[lt], 0, 0, 0);
      }
    }

    // Epilogue: scores = sum_l w[l]*tanh(temp[l]); D layout: col L = 16*lt+l15, row = q*4+r
    float s0p[4] = {0.f, 0.f, 0.f, 0.f};
    float s1p[4] = {0.f, 0.f, 0.f, 0.f};
    #pragma unroll
    for (int lt = 0; lt < 8; ++lt) {
      #pragma unroll
      for (int r = 0; r < 4; ++r) {
        s0p[r] += wreg[lt] * fast_tanh(acc0[lt][r]);
        s1p[r] += wreg[lt] * fast_tanh(acc1[lt][r]);
      }
    }
    // reduce over the 16 L-lanes (xor within 16-lane group) — same order as R1
    #pragma unroll
    for (int r = 0; r < 4; ++r) {
      #pragma unroll
      for (int off = 1; off < 16; off <<= 1) {
        s0p[r] += __shfl_xor(s0p[r], off);
        s1p[r] += __shfl_xor(s1p[r], off);
      }
    }
    if (l15 < 4) {
      float s0 = (l15 == 0) ? s0p[0] : (l15 == 1) ? s0p[1] : (l15 == 2) ? s0p[2] : s0p[3];
      float s1 = (l15 == 0) ? s1p[0] : (l15 == 1) ? s1p[1] : (l15 == 2) ? s1p[2] : s1p[3];
      int n = n0 + q * 4 + l15;
      int b = n >> 12, t = n & 4095;
      // softmax over 2: a0 = sigmoid(s0-s1)
      float e  = __builtin_amdgcn_exp2f(-1.442695041f * (s0 - s1));
      float a0 = __builtin_amdgcn_rcpf(1.0f + e);
      out[b * 8192 + t]        = a0;      // 16 lanes -> 64B contiguous
      out[b * 8192 + 4096 + t] = 1.0f - a0;
    }
  }
}

extern "C" void kernel_launch(void* const* d_in, const int* in_sizes, int n_in,
                              void* d_out, int out_size, void* d_ws, size_t ws_size,
                              hipStream_t stream) {
  const float* h1 = (const float*)d_in[0];   // (32,4096,256) fp32
  const float* h2 = (const float*)d_in[1];   // (32,4096,256) fp32
  const float* w  = (const float*)d_in[2];   // (1,128) fp32
  const float* v  = (const float*)d_in[3];   // (128,256) fp32
  float* out = (float*)d_out;                // (32,2,4096) fp32

  topo_attn_kernel<<<NWG, 512, 0, stream>>>(h1, h2, w, v, out);
}

// Round 3
// 287.531 us; speedup vs baseline: 1.1660x; 1.0655x over previous
//
#include <hip/hip_runtime.h>

// Topo_Attention: out[b,c,t] = softmax_c( sum_l w[l]*tanh(sum_m v[l,m]*h_c[b,t,m]) )
// B=32, T=4096, M=256, L=128.  bf16 MFMA GEMM; memory-bound, HBM floor ~43us.
// R3: both streams packed in one MFMA A-tile (rows 0-7=h1, 8-15=h2) -> acc=32 regs;
//     freed regs fund a depth-3 rolling load prefetch (2 loads/step, issued 2 steps
//     ahead, surviving across iterations -- no barrier in the main loop).
//     V in LDS with +8 padding (stride 264 elts): balanced 8-phase ds_read_b128 and
//     pure-immediate ks offsets. Numerics bit-identical to R1/R2.

typedef unsigned short u16;
typedef unsigned int   u32;
typedef __bf16 bf16x8 __attribute__((ext_vector_type(8)));
typedef float  f32x4  __attribute__((ext_vector_type(4)));

union ABFrag { bf16x8 v; u16 u[8]; uint4 q4; };

__device__ __forceinline__ u16 f2bf(float f) {
  // round-to-nearest-even fp32 -> bf16 (finite inputs; no NaN path)
  u32 u = __float_as_uint(f);
  u += 0x7fffu + ((u >> 16) & 1u);
  return (u16)(u >> 16);
}

__device__ __forceinline__ float fast_tanh(float x) {
  // tanh(x) = 1 - 2/(e^{2x}+1);  e^{2x} = 2^{x*2.885390082}
  float t = __builtin_amdgcn_exp2f(2.885390082f * x);
  return 1.0f - 2.0f * __builtin_amdgcn_rcpf(t + 1.0f);
}

#define NWG     512     // 2 WGs/CU (LDS ~66KB each)
#define ITERS   4       // 512 WGs x 8 waves x 8 rows x 4 iters = 131072 rows
#define VSTRIDE 264     // 256 + 8 pad elems: row stride 528B -> balanced LDS phases

__global__ __launch_bounds__(512, 4) void topo_attn_kernel(
    const float* __restrict__ h1, const float* __restrict__ h2,
    const float* __restrict__ w,  const float* __restrict__ vfp,
    float* __restrict__ out) {
  // V bf16 in LDS, padded layout: element (l,m) at l*VSTRIDE + m.
  __shared__ __align__(16) u16 vlds[128 * VSTRIDE];   // 67584 B

  const int tid = threadIdx.x;

  { // one-time: convert V fp32 -> bf16 into LDS (V stays L2-hot across WGs)
    const float4* src = (const float4*)vfp;
    #pragma unroll
    for (int k = 0; k < 8; ++k) {
      int gi = k * 512 + tid;          // 8-elem group index, 0..4095
      float4 f0 = src[gi * 2];
      float4 f1 = src[gi * 2 + 1];
      ABFrag t;
      t.u[0] = f2bf(f0.x); t.u[1] = f2bf(f0.y); t.u[2] = f2bf(f0.z); t.u[3] = f2bf(f0.w);
      t.u[4] = f2bf(f1.x); t.u[5] = f2bf(f1.y); t.u[6] = f2bf(f1.z); t.u[7] = f2bf(f1.w);
      int l = gi >> 5;                 // 0..127
      int g = gi & 31;                 // 0..31
      *(uint4*)&vlds[l * VSTRIDE + g * 8] = t.q4;
    }
  }
  __syncthreads();                     // only barrier in the kernel

  const int lane = tid & 63;
  const int wave = tid >> 6;           // 0..7
  const int l15  = lane & 15;          // MFMA A-row / D-col lane index
  const int q    = lane >> 4;          // quad: A k = q*8+j ; D row = q*4+reg

  float wreg[8];
  #pragma unroll
  for (int lt = 0; lt < 8; ++lt) wreg[lt] = w[lt * 16 + l15];

  // Per-lane A pointer: rows 0-7 of the tile = h1, rows 8-15 = h2, same t-rows.
  const int row8 = l15 & 7;
  const float* hbase = (l15 < 8) ? h1 : h2;
  const int n0base = blockIdx.x * 64 + wave * 8;      // +it*32768 per iter
  const float4* p = (const float4*)(hbase + (size_t)(n0base + row8) * 256) + q * 2;

  // LDS byte base per lt: elem (lt*16+l15, q*8), read at +ks*64 bytes (immediate).
  int vbase[8];
  #pragma unroll
  for (int lt = 0; lt < 8; ++lt)
    vbase[lt] = ((lt * 16 + l15) * VSTRIDE + q * 8) * 2;

  // Rolling depth-3 prefetch over flattened steps s = it*8+ks (2 loads/step).
  float4 bufA[3], bufB[3];
  bufA[0] = p[0]; bufB[0] = p[1];      // s=0 (it0,ks0)
  bufA[1] = p[8]; bufB[1] = p[9];      // s=1 (it0,ks1)

  #pragma unroll
  for (int it = 0; it < ITERS; ++it) {
    f32x4 acc[8];
    #pragma unroll
    for (int lt = 0; lt < 8; ++lt) acc[lt] = (f32x4){0.f, 0.f, 0.f, 0.f};

    #pragma unroll
    for (int ks = 0; ks < 8; ++ks) {
      const int s = it * 8 + ks;
      if (s + 2 < ITERS * 8) {         // issue step s+2 (compile-time predicate)
        const int s2  = s + 2;
        const int it2 = s2 >> 3, ks2 = s2 & 7;
        const float4* pp = p + it2 * 2097152 + ks2 * 8;  // it-stride: 32768 rows
        bufA[s2 % 3] = pp[0];
        bufB[s2 % 3] = pp[1];
      }
      float4 fa = bufA[s % 3], fb = bufB[s % 3];
      ABFrag a;
      a.u[0] = f2bf(fa.x); a.u[1] = f2bf(fa.y); a.u[2] = f2bf(fa.z); a.u[3] = f2bf(fa.w);
      a.u[4] = f2bf(fb.x); a.u[5] = f2bf(fb.y); a.u[6] = f2bf(fb.z); a.u[7] = f2bf(fb.w);
      #pragma unroll
      for (int lt = 0; lt < 8; ++lt) {
        bf16x8 bfr = *(const bf16x8*)((const char*)vlds + (vbase[lt] + ks * 64));
        acc[lt] = __builtin_amdgcn_mfma_f32_16x16x32_bf16(a.v, bfr, acc[lt], 0, 0, 0);
      }
    }

    // Epilogue: s_p[r] = sum_l w[l]*tanh(temp); D: col L=16*lt+l15, row m=q*4+r.
    // Rows m=0..7 are stream-0 scores, m=8..15 stream-1 (same t-rows).
    float s_p[4] = {0.f, 0.f, 0.f, 0.f};
    #pragma unroll
    for (int lt = 0; lt < 8; ++lt) {
      #pragma unroll
      for (int r = 0; r < 4; ++r)
        s_p[r] += wreg[lt] * fast_tanh(acc[lt][r]);
    }
    // reduce over the 16 D-col lanes (same order as R1/R2)
    #pragma unroll
    for (int r = 0; r < 4; ++r) {
      #pragma unroll
      for (int off = 1; off < 16; off <<= 1)
        s_p[r] += __shfl_xor(s_p[r], off);
    }
    // after reduce all 16 lanes hold s_p[0..3]; pair q <-> q^2 carries s0<->s1
    const int r = l15 & 3;
    float sel = (r == 0) ? s_p[0] : (r == 1) ? s_p[1] : (r == 2) ? s_p[2] : s_p[3];
    float oth = __shfl_xor(sel, 32);   // partner quad's score (all lanes execute)
    if (q < 2 && l15 < 4) {
      int n = n0base + it * 32768 + q * 4 + l15;   // row 0..7 of this tile
      int b = n >> 12, t = n & 4095;
      float e  = __builtin_amdgcn_exp2f(-1.442695041f * (sel - oth));
      float a0 = __builtin_amdgcn_rcpf(1.0f + e);
      out[b * 8192 + t]        = a0;
      out[b * 8192 + 4096 + t] = 1.0f - a0;
    }
  }
}

extern "C" void kernel_launch(void* const* d_in, const int* in_sizes, int n_in,
                              void* d_out, int out_size, void* d_ws, size_t ws_size,
                              hipStream_t stream) {
  const float* h1 = (const float*)d_in[0];   // (32,4096,256) fp32
  const float* h2 = (const float*)d_in[1];   // (32,4096,256) fp32
  const float* w  = (const float*)d_in[2];   // (1,128) fp32
  const float* v  = (const float*)d_in[3];   // (128,256) fp32
  float* out = (float*)d_out;                // (32,2,4096) fp32

  topo_attn_kernel<<<NWG, 512, 0, stream>>>(h1, h2, w, v, out);
}

// Round 4
// 281.158 us; speedup vs baseline: 1.1924x; 1.0227x over previous
//
#include <hip/hip_runtime.h>

// Topo_Attention: out[b,c,t] = softmax_c( sum_l w[l]*tanh(sum_m v[l,m]*h_c[b,t,m]) )
// B=32, T=4096, M=256, L=128.  bf16 MFMA GEMM; memory-bound.
// R4: A staged via global_load_lds (full-line DMA, 8x128B lines/instr, each line
//     requested once) into per-wave 3-slot rolling LDS buffers, prefetch 2 steps
//     ahead, no barriers in the main loop (explicit s_waitcnt vmcnt(N)).
//     Conflict-free A frag reads via rotate of the *global* source chunk (DMA dest
//     is lane*16, can't scatter). V back to R1 rotate layout (padded was 4x worse).
//     LDS 112KB dynamic -> 1 WG/CU (8 waves). Numerics bit-identical to R1-R3.

typedef unsigned short u16;
typedef unsigned int   u32;
typedef __bf16 bf16x8 __attribute__((ext_vector_type(8)));
typedef float  f32x4  __attribute__((ext_vector_type(4)));

union ABFrag { bf16x8 v; u16 u[8]; uint4 q4; };

__device__ __forceinline__ u16 f2bf(float f) {
  // round-to-nearest-even fp32 -> bf16 (finite inputs; no NaN path)
  u32 u = __float_as_uint(f);
  u += 0x7fffu + ((u >> 16) & 1u);
  return (u16)(u >> 16);
}

__device__ __forceinline__ float fast_tanh(float x) {
  float t = __builtin_amdgcn_exp2f(2.885390082f * x);
  return 1.0f - 2.0f * __builtin_amdgcn_rcpf(t + 1.0f);
}

typedef const __attribute__((address_space(1))) void gvoid;
typedef __attribute__((address_space(3))) void lvoid;

__device__ __forceinline__ void dma16(const char* g, char* l) {
  __builtin_amdgcn_global_load_lds((gvoid*)g, (lvoid*)l, 16, 0, 0);
}

#define NWG    256
#define ITERS  8
#define TOT    (ITERS * 8)
#define ITSTR  (NWG * 64 * 1024)   // per-iter global byte stride (16384 rows)
#define SMEMSZ (65536 + 8 * 3 * 2048)   // V 64KB + 8 waves x 3 slots x 2KB

__global__ __launch_bounds__(512, 2) void topo_attn_kernel(
    const float* __restrict__ h1, const float* __restrict__ h2,
    const float* __restrict__ w,  const float* __restrict__ vfp,
    float* __restrict__ out) {
  extern __shared__ __align__(16) char smem[];
  u16*  vlds   = (u16*)smem;                 // V bf16, R1 rotate layout (64KB)
  char* albase = smem + 65536;               // A staging (48KB)

  const int tid = threadIdx.x;

  { // one-time: convert V fp32 -> bf16 into LDS, rotate swizzle (chunk g -> (g+l)&31)
    const float4* src = (const float4*)vfp;
    #pragma unroll
    for (int k = 0; k < 8; ++k) {
      int gi = k * 512 + tid;            // 8-elem group index, 0..4095
      float4 f0 = src[gi * 2];
      float4 f1 = src[gi * 2 + 1];
      ABFrag t;
      t.u[0] = f2bf(f0.x); t.u[1] = f2bf(f0.y); t.u[2] = f2bf(f0.z); t.u[3] = f2bf(f0.w);
      t.u[4] = f2bf(f1.x); t.u[5] = f2bf(f1.y); t.u[6] = f2bf(f1.z); t.u[7] = f2bf(f1.w);
      int l = gi >> 5;                   // 0..127
      int g = gi & 31;                   // 0..31
      *(uint4*)&vlds[(l << 8) + (((g + l) & 31) << 3)] = t.q4;
    }
  }
  __syncthreads();                       // only barrier in the kernel

  const int lane = tid & 63;
  const int wave = tid >> 6;             // 0..7
  const int l15  = lane & 15;            // MFMA A-row / D-col lane index
  const int q    = lane >> 4;            // quad: A k = q*8+j ; D row = q*4+reg

  float wreg[8];
  #pragma unroll
  for (int lt = 0; lt < 8; ++lt) wreg[lt] = w[lt * 16 + l15];

  char* aslot = albase + wave * 6144;    // 3 slots x 2048B, wave-private

  // DMA source mapping: lane i deposits at slot + i*16 (HW-fixed). We want LDS
  // position (row r=i>>3, chunk j=i&7) to hold global chunk c=(j-r)&7 -> rotated
  // frag reads hit all 8 bank groups evenly. Same 128B lines, permuted lanes.
  const int rr = lane >> 3;              // row within 8-row block
  const int cc = lane & 7;               // dest chunk
  const int gchunk = (cc - rr) & 7;      // source chunk within the 128B k-slice

  const int n0base = (blockIdx.x * 8 + wave) * 8;   // rows for it=0
  const char* g1 = (const char*)h1 + (size_t)(n0base + rr) * 1024 + gchunk * 16;
  const char* g2 = (const char*)h2 + (size_t)(n0base + rr) * 1024 + gchunk * 16;

  // A-frag LDS read offsets (row r=l15&7, block=l15>>3, chunks 2q,2q+1 rotated):
  const int r7 = l15 & 7;
  const int fragbase = (l15 >> 3) * 1024 + r7 * 128;
  const int j1 = ((2 * q + r7) & 7) * 16;
  const int j2 = ((2 * q + 1 + r7) & 7) * 16;

  // V LDS byte base per lt (R1 rotate layout), read at ks-dependent rotation.
  // Prologue: stage steps 0 and 1.
  {
    dma16(g1, aslot);            dma16(g2, aslot + 1024);
    dma16(g1 + 128, aslot + 2048); dma16(g2 + 128, aslot + 2048 + 1024);
  }

  #pragma unroll
  for (int it = 0; it < ITERS; ++it) {
    f32x4 acc[8];
    #pragma unroll
    for (int lt = 0; lt < 8; ++lt) acc[lt] = (f32x4){0.f, 0.f, 0.f, 0.f};

    #pragma unroll
    for (int ks = 0; ks < 8; ++ks) {
      const int s = it * 8 + ks;
      if (s + 2 < TOT) {                 // stage step s+2 (compile-time predicate)
        const int s2 = s + 2;
        const size_t off = (size_t)(s2 >> 3) * ITSTR + (s2 & 7) * 128;
        char* dst = aslot + (s2 % 3) * 2048;
        dma16(g1 + off, dst);
        dma16(g2 + off, dst + 1024);
      }
      // wait for step s's two DMAs (FIFO: >=4 newer ops always issued after them,
      // except at the tail where fewer prefetches exist)
      if (s + 2 < TOT)      asm volatile("s_waitcnt vmcnt(4)" ::: "memory");
      else if (s + 1 < TOT) asm volatile("s_waitcnt vmcnt(2)" ::: "memory");
      else                  asm volatile("s_waitcnt vmcnt(0)" ::: "memory");

      const char* ab = aslot + (s % 3) * 2048 + fragbase;
      float4 fa = *(const float4*)(ab + j1);   // k = q*8 .. q*8+3
      float4 fb = *(const float4*)(ab + j2);   // k = q*8+4 .. q*8+7
      ABFrag a;
      a.u[0] = f2bf(fa.x); a.u[1] = f2bf(fa.y); a.u[2] = f2bf(fa.z); a.u[3] = f2bf(fa.w);
      a.u[4] = f2bf(fb.x); a.u[5] = f2bf(fb.y); a.u[6] = f2bf(fb.z); a.u[7] = f2bf(fb.w);
      #pragma unroll
      for (int lt = 0; lt < 8; ++lt) {
        const int l = (lt << 4) + l15;
        bf16x8 bfr = *(const bf16x8*)&vlds[(l << 8) + (((4 * ks + q + l) & 31) << 3)];
        acc[lt] = __builtin_amdgcn_mfma_f32_16x16x32_bf16(a.v, bfr, acc[lt], 0, 0, 0);
      }
    }

    // Epilogue: s_p[r] = sum_l w[l]*tanh(temp); D: col L=16*lt+l15, row m=q*4+r.
    // Rows m=0..7 are stream-0 (h1) scores, m=8..15 stream-1 (h2), same t-rows.
    float s_p[4] = {0.f, 0.f, 0.f, 0.f};
    #pragma unroll
    for (int lt = 0; lt < 8; ++lt) {
      #pragma unroll
      for (int r = 0; r < 4; ++r)
        s_p[r] += wreg[lt] * fast_tanh(acc[lt][r]);
    }
    #pragma unroll
    for (int r = 0; r < 4; ++r) {
      #pragma unroll
      for (int off = 1; off < 16; off <<= 1)
        s_p[r] += __shfl_xor(s_p[r], off);
    }
    const int r = l15 & 3;
    float sel = (r == 0) ? s_p[0] : (r == 1) ? s_p[1] : (r == 2) ? s_p[2] : s_p[3];
    float oth = __shfl_xor(sel, 32);     // partner quad carries the other stream
    if (q < 2 && l15 < 4) {
      int n = n0base + it * (NWG * 64) + q * 4 + l15;
      int b = n >> 12, t = n & 4095;
      float e  = __builtin_amdgcn_exp2f(-1.442695041f * (sel - oth));
      float a0 = __builtin_amdgcn_rcpf(1.0f + e);
      out[b * 8192 + t]        = a0;
      out[b * 8192 + 4096 + t] = 1.0f - a0;
    }
  }
}

extern "C" void kernel_launch(void* const* d_in, const int* in_sizes, int n_in,
                              void* d_out, int out_size, void* d_ws, size_t ws_size,
                              hipStream_t stream) {
  const float* h1 = (const float*)d_in[0];   // (32,4096,256) fp32
  const float* h2 = (const float*)d_in[1];   // (32,4096,256) fp32
  const float* w  = (const float*)d_in[2];   // (1,128) fp32
  const float* v  = (const float*)d_in[3];   // (128,256) fp32
  float* out = (float*)d_out;                // (32,2,4096) fp32

  static int attr_set = 0;   // idempotent config, safe under graph capture
  (void)attr_set;
  hipFuncSetAttribute((const void*)topo_attn_kernel,
                      hipFuncAttributeMaxDynamicSharedMemorySize, SMEMSZ);
  topo_attn_kernel<<<NWG, 512, SMEMSZ, stream>>>(h1, h2, w, v, out);
}